// Round 3
// baseline (240.149 us; speedup 1.0000x reference)
//
#include <hip/hip_runtime.h>

// ChineseCLIP vision attention, MI355X bf16-MFMA pipeline. Round 7:
//  - qkv_gemm: 256x128 tile, BK=32, wave-tile 64x64 (acc=64 VGPR, total
//    ~115 <= 128 via __launch_bounds__(512,4)) -> 48KB LDS -> 2 blocks/CU,
//    16 waves/CU. Bet: cross-block TLP absorbs barrier/lgkm stalls that
//    R5/R6's 1-block 8-phase could not hide (R6 depth experiment: neutral).
//    BK=32 rows (64B) spread banks naturally -> swizzle dropped.
//    Per K-tile: reads -> lgkm0 -> barrier -> stage(t+2) -> 16 MFMA ->
//    vmcnt(3) -> barrier.  Grid 792 = 33x24.
// B=32, T=257, D=1024, H=16, HD=64.

#define B_   32
#define T_   257
#define TP   272
#define H_   16
#define HD_  64
#define D_   1024
#define NTOK 8224
#define BH_  512
#define FRAG_PER_BH 17408   // TP*HD elements per (b,h) in frag-major arrays

typedef __bf16 bf16;
typedef __bf16 bf16x4 __attribute__((ext_vector_type(4)));
typedef __bf16 bf16x8 __attribute__((ext_vector_type(8)));
typedef short  s16x4  __attribute__((ext_vector_type(4)));
typedef short  s16x8  __attribute__((ext_vector_type(8)));
typedef float  floatx4 __attribute__((ext_vector_type(4)));

static constexpr size_t SZ_XB   = (size_t)NTOK * D_ * 2;
static constexpr size_t SZ_WQKV = (size_t)3 * D_ * D_ * 2;
static constexpr size_t SZ_W    = (size_t)D_ * D_ * 2;
static constexpr size_t SZ_QK   = (size_t)BH_ * FRAG_PER_BH * 2;

static constexpr size_t OFF_XB   = 0;
static constexpr size_t OFF_WQKV = OFF_XB + SZ_XB;
static constexpr size_t OFF_WO   = OFF_WQKV + SZ_WQKV;
static constexpr size_t OFF_Q    = OFF_WO + SZ_W;
static constexpr size_t OFF_K    = OFF_Q + SZ_QK;
static constexpr size_t OFF_V    = OFF_K + SZ_QK;
static constexpr size_t OFF_CTX  = OFF_V + SZ_QK;

#define GLD16(gp, lp)                                                        \
  __builtin_amdgcn_global_load_lds(                                          \
      (const __attribute__((address_space(1))) void*)(gp),                   \
      (__attribute__((address_space(3))) void*)(lp), 16, 0, 0)

// ---------------- fp32 -> bf16 casts (single launch) ----------------
__global__ void cast_all_kernel(const float* __restrict__ hs,
                                const float* __restrict__ Wq, const float* __restrict__ Wk,
                                const float* __restrict__ Wv, const float* __restrict__ Wo,
                                bf16* __restrict__ xb, bf16* __restrict__ wqkv,
                                bf16* __restrict__ wob) {
  const int y = blockIdx.y;
  const float* s;
  bf16* d;
  int n4;
  if (y == 0) {
    s = hs; d = xb; n4 = NTOK * D_ / 4;
  } else {
    int z = y - 1;
    s = (z == 0) ? Wq : (z == 1) ? Wk : (z == 2) ? Wv : Wo;
    d = (z < 3) ? wqkv + (size_t)z * D_ * D_ : wob;
    n4 = D_ * D_ / 4;
  }
  int i = blockIdx.x * blockDim.x + threadIdx.x;
  int stride = gridDim.x * blockDim.x;
  for (int idx = i; idx < n4; idx += stride) {
    float4 v = reinterpret_cast<const float4*>(s)[idx];
    bf16x4 o;
    o[0] = (bf16)v.x; o[1] = (bf16)v.y; o[2] = (bf16)v.z; o[3] = (bf16)v.w;
    reinterpret_cast<bf16x4*>(d)[idx] = o;
  }
}

// Frag-major layouts (element offsets within one bh's 17408 elems):
// Q/K (A/B-op of 16x16x32): [kt(17)][dc(8)][ki(16)][8]  (t=kt*16+ki, d=dc*8+e)
// V   (A-op of 16x16x16, dt-paired): [kt(17)][p(2)][q2(4)][d16(16)][dp(2)][ki(4)]
//     t = kt*16 + q2*4 + ki, d = p*32 + dp*16 + d16.

// ================= fused QKV GEMM: 256x128 tile, BK=32, 2 blocks/CU ======
// 512 threads = 8 waves (4M x 2N), wave-tile 64x64. K=1024 -> 32 K-tiles.
// LDS (48KB): A [2][256][32] elems at 0, B [2][128][32] at 16384.
// No swizzle: 64B rows spread banks via (rh&1)*16 + quad*4 (8 words/bank,
// b128 floor). Stage(t+2) issued into the buffer this tile just finished
// reading (safe: lgkm0+barrier precede it). vmcnt(3) = t+1 fully landed.

#define KTILE(TT, CC)                                                        \
  do {                                                                       \
    const int ktn_ = ((TT) + 2 < 32) ? (TT) + 2 : 31;                        \
    _Pragma("unroll") for (int mi_ = 0; mi_ < 4; mi_++)                      \
      af[mi_] = *reinterpret_cast<const bf16x8*>(                            \
          smem + (CC) * 8192 + (arow + mi_ * 16) * 32 + quad * 8);           \
    _Pragma("unroll") for (int nj_ = 0; nj_ < 4; nj_++)                      \
      bfr[nj_] = *reinterpret_cast<const bf16x8*>(                           \
          smem + 16384 + (CC) * 4096 + (brow + nj_ * 16) * 32 + quad * 8);   \
    asm volatile("s_waitcnt lgkmcnt(0)" ::: "memory");                       \
    __builtin_amdgcn_sched_barrier(0);                                       \
    __builtin_amdgcn_s_barrier();                                            \
    /* buffer CC is dead now -> stage tile TT+2 into it */                   \
    GLD16(aSrc0 + ktn_ * 32, dstA0 + (CC) * 8192);                           \
    GLD16(aSrc1 + ktn_ * 32, dstA1 + (CC) * 8192);                           \
    GLD16(bSrc + ktn_ * 32, dstB + (CC) * 4096);                             \
    __builtin_amdgcn_sched_barrier(0);                                       \
    __builtin_amdgcn_s_setprio(1);                                           \
    _Pragma("unroll") for (int mi_ = 0; mi_ < 4; mi_++)                      \
      _Pragma("unroll") for (int nj_ = 0; nj_ < 4; nj_++)                    \
        acc[mi_][nj_] = __builtin_amdgcn_mfma_f32_16x16x32_bf16(             \
            af[mi_], bfr[nj_], acc[mi_][nj_], 0, 0, 0);                      \
    __builtin_amdgcn_s_setprio(0);                                           \
    asm volatile("s_waitcnt vmcnt(3)" ::: "memory");                         \
    __builtin_amdgcn_s_barrier();                                            \
  } while (0)

__global__ __launch_bounds__(512, 4) void qkv_gemm(
    const bf16* __restrict__ xb, const bf16* __restrict__ wqkv,
    const float* __restrict__ bq, const float* __restrict__ bk,
    const float* __restrict__ bv,
    bf16* __restrict__ Qf, bf16* __restrict__ Kf, bf16* __restrict__ Vf) {
  __shared__ bf16 smem[24576];   // 48KB

  const int linear = blockIdx.x;
  const int mt = linear / 24, nt = linear % 24;
  const int m0 = mt * 256, n0 = nt * 128;
  const int tid = threadIdx.x;
  const int lane = tid & 63, w = tid >> 6;
  const int n15 = lane & 15, quad = lane >> 4;
  const int wr4 = w >> 1, wn = w & 1;

  const int arow = wr4 * 64 + n15;   // A rows this wave reads (base)
  const int brow = wn * 64 + n15;    // B rows this wave reads (base)

  // staging source pointers (per-thread, fixed; kt advances by +kt*32 elems)
  const int srow = lane >> 2, sseg = (lane & 3) * 8;
  int gmA0 = m0 + (w * 2 + 0) * 16 + srow; if (gmA0 > NTOK - 1) gmA0 = NTOK - 1;
  int gmA1 = m0 + (w * 2 + 1) * 16 + srow; if (gmA1 > NTOK - 1) gmA1 = NTOK - 1;
  const bf16* aSrc0 = xb + (size_t)gmA0 * D_ + sseg;
  const bf16* aSrc1 = xb + (size_t)gmA1 * D_ + sseg;
  const bf16* bSrc  = wqkv + (size_t)(n0 + w * 16 + srow) * D_ + sseg;
  // LDS dests (wave-uniform; HW adds lane*16B)
  bf16* dstA0 = smem + (w * 2 + 0) * 512;
  bf16* dstA1 = smem + (w * 2 + 1) * 512;
  bf16* dstB  = smem + 16384 + w * 512;

  floatx4 acc[4][4] = {};
  bf16x8 af[4], bfr[4];

  // prologue: tile0 -> buf0, tile1 -> buf1; vmcnt(3) = tile0 landed.
  GLD16(aSrc0, dstA0); GLD16(aSrc1, dstA1); GLD16(bSrc, dstB);
  GLD16(aSrc0 + 32, dstA0 + 8192); GLD16(aSrc1 + 32, dstA1 + 8192);
  GLD16(bSrc + 32, dstB + 4096);
  asm volatile("s_waitcnt vmcnt(3)" ::: "memory");
  __builtin_amdgcn_s_barrier();

  for (int t = 0; t < 32; t += 2) {
    KTILE(t, 0);
    KTILE(t + 1, 1);
  }

  // drain tail junk stages before reusing LDS.
  asm volatile("s_waitcnt vmcnt(0)" ::: "memory");
  __builtin_amdgcn_s_barrier();

  // ---- epilogue: two 128-row half-passes, frag-major stores ----
  const int z = nt >> 3;                 // 0=Q 1=K 2=V
  bf16* zdst = (z == 0) ? Qf : (z == 1) ? Kf : Vf;
  const float scale = (z == 0) ? 0.125f : 1.0f;
  const float* bias = (z == 0) ? bq : (z == 1) ? bk : bv;
  const int znb = (nt & 7) * 128;        // col base within the 1024-wide slab

  for (int h = 0; h < 2; h++) {
    // waves with (wr4>>1)==h own rows [h*128, h*128+128)
    if ((wr4 >> 1) == h) {
      float bvv[4];
#pragma unroll
      for (int nj = 0; nj < 4; nj++)
        bvv[nj] = bias[znb + wn * 64 + nj * 16 + n15];
#pragma unroll
      for (int mi = 0; mi < 4; mi++)
#pragma unroll
        for (int nj = 0; nj < 4; nj++) {
          int colL = wn * 64 + nj * 16 + n15;
#pragma unroll
          for (int r = 0; r < 4; r++) {
            int rowL = (wr4 & 1) * 64 + mi * 16 + quad * 4 + r;
            smem[rowL * 136 + colL] = (bf16)((acc[mi][nj][r] + bvv[nj]) * scale);
          }
        }
    }
    __syncthreads();

    const int mh0 = m0 + h * 128;
    int nU = 0, nA = 0, tgA0 = 0, tA = 0, tEndA = 0, tEndB = 0, bA = 0;
    int span = NTOK - mh0;
    if (span > 0) {
      if (span > 128) span = 128;
      bA = mh0 / T_;
      tA = mh0 - bA * T_;
      tEndA = (tA + span < T_) ? tA + span : T_;
      tgA0 = tA >> 4;
      nA = ((tEndA - 1) >> 4) - tgA0 + 1;
      nU = nA;
      if (tA + span > T_ && bA + 1 < B_) {
        tEndB = tA + span - T_;
        nU += ((tEndB - 1) >> 4) + 1;
      }
    }

    for (int u = w; u < nU * 2; u += 8) {
      int g = u >> 1, hh = u & 1;
      int bb, tg, tlo, thi;
      if (g < nA) {
        bb = bA; tg = tgA0 + g;
        tlo = (tA > tg * 16) ? tA : tg * 16;
        int te = tg * 16 + 16; thi = (te < tEndA) ? te : tEndA;
      } else {
        bb = bA + 1; tg = g - nA; tlo = tg * 16;
        int te = tg * 16 + 16; thi = (te < tEndB) ? te : tEndB;
      }
      const int hgl = (nt & 7) * 2 + hh;   // head within slab
      bf16* gb = zdst + (size_t)(bb * H_ + hgl) * FRAG_PER_BH + tg * 1024;
      const int hc = hh * 64;
      if (z != 2) {
        int ki = lane & 15, dc = lane >> 4;
        int tt = tg * 16 + ki;
        if (tt >= tlo && tt < thi) {
          int rowL = bb * T_ + tt - mh0;
          bf16x8 v0 = *reinterpret_cast<const bf16x8*>(smem + rowL * 136 + hc + dc * 8);
          bf16x8 v1 = *reinterpret_cast<const bf16x8*>(smem + rowL * 136 + hc + 32 + dc * 8);
          *reinterpret_cast<bf16x8*>(gb + dc * 128 + ki * 8) = v0;
          *reinterpret_cast<bf16x8*>(gb + 512 + dc * 128 + ki * 8) = v1;
        }
      } else {
        int q2 = (lane >> 4) & 3, d16 = lane & 15;
        int tb = tg * 16 + q2 * 4;
        bool full = (tb >= tlo) && (tb + 3 < thi);
#pragma unroll
        for (int p = 0; p < 2; p++) {
          bf16x8 vv;
#pragma unroll
          for (int dp = 0; dp < 2; dp++)
#pragma unroll
            for (int ki = 0; ki < 4; ki++) {
              int tt = tb + ki;
              int rr = (bb * T_ + tt - mh0) & 127;   // safe for masked elems
              vv[dp * 4 + ki] = smem[rr * 136 + hc + p * 32 + dp * 16 + d16];
            }
          bf16* cp = gb + (p * 4 + q2) * 128 + d16 * 8;
          if (full) {
            *reinterpret_cast<bf16x8*>(cp) = vv;
          } else {
#pragma unroll
            for (int dp = 0; dp < 2; dp++)
#pragma unroll
              for (int ki = 0; ki < 4; ki++) {
                int tt = tb + ki;
                if (tt >= tlo && tt < thi) cp[dp * 4 + ki] = vv[dp * 4 + ki];
              }
          }
        }
      }
    }
    __syncthreads();
  }
}

// ---------------- fused attention (LDS-staged K/V) ----------------
// grid = 512 (one block per bh), 4 waves; wave w handles q-tiles w, w+4, ...
__global__ __launch_bounds__(256) void attn_kernel(
    const bf16* __restrict__ Qf, const bf16* __restrict__ Kf,
    const bf16* __restrict__ Vf, bf16* __restrict__ ctx) {
  __shared__ bf16 smem[34816];   // K (17408) then V (17408)

  const int bh = blockIdx.x;
  const int tid = threadIdx.x;
  const int lane = tid & 63, w = tid >> 6;
  const int n15 = lane & 15, quad = lane >> 4;
  const int b = bh >> 4, h = bh & 15;

  const bf16* Qb = Qf + (size_t)bh * FRAG_PER_BH;
  const bf16* Kb = Kf + (size_t)bh * FRAG_PER_BH;
  const bf16* Vb = Vf + (size_t)bh * FRAG_PER_BH;

  // stage K and V: 68 chunks of 1KB, 17 per wave
#pragma unroll
  for (int j = 0; j < 17; j++) {
    int c = w * 17 + j;
    const bf16* src = (c < 34) ? (Kb + c * 512) : (Vb + (c - 34) * 512);
    GLD16(src + lane * 8, smem + c * 512);
  }
  __syncthreads();
  const bf16* Ksh = smem;
  const bf16* Vsh = smem + 17408;

  const int fo = quad * 128 + n15 * 8;

  for (int qt = w; qt < 17; qt += 4) {
    bf16x8 qb0 = *reinterpret_cast<const bf16x8*>(Qb + qt * 1024 + fo);
    bf16x8 qb1 = *reinterpret_cast<const bf16x8*>(Qb + qt * 1024 + 512 + fo);

    floatx4 s[17];
#pragma unroll
    for (int kt = 0; kt < 17; kt++) {
      bf16x8 ka0 = *reinterpret_cast<const bf16x8*>(Ksh + kt * 1024 + fo);
      bf16x8 ka1 = *reinterpret_cast<const bf16x8*>(Ksh + kt * 1024 + 512 + fo);
      floatx4 c = {};
      c = __builtin_amdgcn_mfma_f32_16x16x32_bf16(ka0, qb0, c, 0, 0, 0);
      c = __builtin_amdgcn_mfma_f32_16x16x32_bf16(ka1, qb1, c, 0, 0, 0);
      s[kt] = c;
    }
    // keys 257..271 invalid: tile 16 holds keys 256+quad*4+r; only 256 valid
    s[16][1] = -1e30f; s[16][2] = -1e30f; s[16][3] = -1e30f;
    if (quad != 0) s[16][0] = -1e30f;

    float m0 = -1e30f;
#pragma unroll
    for (int kt = 0; kt < 17; kt++)
#pragma unroll
      for (int r = 0; r < 4; r++) m0 = fmaxf(m0, s[kt][r]);
    m0 = fmaxf(m0, __shfl_xor(m0, 16));
    m0 = fmaxf(m0, __shfl_xor(m0, 32));

    float sum = 0.f;
    s16x4 pb[17];
#pragma unroll
    for (int kt = 0; kt < 17; kt++) {
      bf16x4 ph;
#pragma unroll
      for (int r = 0; r < 4; r++) {
        float p = __expf(s[kt][r] - m0);
        sum += p;
        ph[r] = (bf16)p;
      }
      pb[kt] = __builtin_bit_cast(s16x4, ph);
    }
    sum += __shfl_xor(sum, 16);
    sum += __shfl_xor(sum, 32);

    floatx4 o[4] = {};
#pragma unroll
    for (int kt = 0; kt < 17; kt++) {
#pragma unroll
      for (int p = 0; p < 2; p++) {
        bf16x8 vv = *reinterpret_cast<const bf16x8*>(
            Vsh + ((kt * 2 + p) * 4 + quad) * 128 + n15 * 8);
        s16x8 v16 = __builtin_bit_cast(s16x8, vv);
        s16x4 vlo = __builtin_shufflevector(v16, v16, 0, 1, 2, 3);
        s16x4 vhi = __builtin_shufflevector(v16, v16, 4, 5, 6, 7);
        o[p * 2]     = __builtin_amdgcn_mfma_f32_16x16x16bf16_1k(vlo, pb[kt], o[p * 2], 0, 0, 0);
        o[p * 2 + 1] = __builtin_amdgcn_mfma_f32_16x16x16bf16_1k(vhi, pb[kt], o[p * 2 + 1], 0, 0, 0);
      }
    }

    int q = qt * 16 + n15;
    if (q < T_) {
      float inv = 1.0f / sum;
      size_t ob = ((size_t)(b * T_ + q)) * D_ + h * 64 + quad * 4;
#pragma unroll
      for (int dt = 0; dt < 4; dt++) {
        bf16x4 ov;
#pragma unroll
        for (int r = 0; r < 4; r++) ov[r] = (bf16)(o[dt][r] * inv);
        *reinterpret_cast<bf16x4*>(ctx + ob + dt * 16) = ov;
      }
    }
  }
}

// ---------------- output projection GEMM (fp32 out) ----------------
__global__ __launch_bounds__(256) void o_gemm(
    const bf16* __restrict__ ctx, const bf16* __restrict__ wo,
    const float* __restrict__ bo, float* __restrict__ out) {
  __shared__ bf16 Ash[128 * 32];
  __shared__ bf16 Bsh[128 * 32];

  const int linear = blockIdx.x;
  const int nbase = (linear & 7) * 128;
  const int mbase = (linear >> 3) * 128;
  const int tid = threadIdx.x;
  const int lane = tid & 63;
  const int w = tid >> 6;
  const int wr = w >> 1, wc = w & 1;
  const int n15 = lane & 15, quad = lane >> 4;

  const int lrow = lane >> 2;
  const int lseg = (lane & 3) * 8;

  floatx4 acc[4][4] = {};

  for (int k0 = 0; k0 < D_; k0 += 32) {
#pragma unroll
    for (int c = 0; c < 2; c++) {
      int r0 = w * 32 + c * 16;
      int row = r0 + lrow;
      int gm = mbase + row; if (gm > NTOK - 1) gm = NTOK - 1;
      GLD16(ctx + (size_t)gm * D_ + k0 + lseg, Ash + r0 * 32);
      GLD16(wo + (size_t)(nbase + row) * D_ + k0 + lseg, Bsh + r0 * 32);
    }
    __syncthreads();
    bf16x8 af[4], bfr[4];
#pragma unroll
    for (int i = 0; i < 4; i++) {
      af[i]  = *reinterpret_cast<const bf16x8*>(Ash + (wr * 64 + i * 16 + n15) * 32 + quad * 8);
      bfr[i] = *reinterpret_cast<const bf16x8*>(Bsh + (wc * 64 + i * 16 + n15) * 32 + quad * 8);
    }
#pragma unroll
    for (int i = 0; i < 4; i++)
#pragma unroll
      for (int j = 0; j < 4; j++)
        acc[i][j] = __builtin_amdgcn_mfma_f32_16x16x32_bf16(af[i], bfr[j], acc[i][j], 0, 0, 0);
    __syncthreads();
  }

#pragma unroll
  for (int i = 0; i < 4; i++) {
    int rowb = mbase + wr * 64 + i * 16 + quad * 4;
#pragma unroll
    for (int j = 0; j < 4; j++) {
      int col = nbase + wc * 64 + j * 16 + n15;
      float bval = bo[col];
#pragma unroll
      for (int r = 0; r < 4; r++) {
        int m = rowb + r;
        if (m < NTOK) out[(size_t)m * D_ + col] = acc[i][j][r] + bval;
      }
    }
  }
}

extern "C" void kernel_launch(void* const* d_in, const int* in_sizes, int n_in,
                              void* d_out, int out_size, void* d_ws, size_t ws_size,
                              hipStream_t stream) {
  const float* hs = (const float*)d_in[0];
  const float* Wq = (const float*)d_in[1];
  const float* bq = (const float*)d_in[2];
  const float* Wk = (const float*)d_in[3];
  const float* bk = (const float*)d_in[4];
  const float* Wv = (const float*)d_in[5];
  const float* bv = (const float*)d_in[6];
  const float* Wo = (const float*)d_in[7];
  const float* bo = (const float*)d_in[8];

  char* ws = (char*)d_ws;
  bf16* xb   = (bf16*)(ws + OFF_XB);
  bf16* wqkv = (bf16*)(ws + OFF_WQKV);
  bf16* wob  = (bf16*)(ws + OFF_WO);
  bf16* Qfw  = (bf16*)(ws + OFF_Q);
  bf16* Kfw  = (bf16*)(ws + OFF_K);
  bf16* Vfw  = (bf16*)(ws + OFF_V);
  bf16* ctx  = (bf16*)(ws + OFF_CTX);

  cast_all_kernel<<<dim3(512, 5), 256, 0, stream>>>(hs, Wq, Wk, Wv, Wo,
                                                    xb, wqkv, wob);

  qkv_gemm<<<792, 512, 0, stream>>>(xb, wqkv, bq, bk, bv, Qfw, Kfw, Vfw);
  attn_kernel<<<BH_, 256, 0, stream>>>(Qfw, Kfw, Vfw, ctx);
  o_gemm<<<520, 256, 0, stream>>>(ctx, wob, bo, (float*)d_out);
}

// Round 4
// 234.804 us; speedup vs baseline: 1.0228x; 1.0228x over previous
//
#include <hip/hip_runtime.h>

// ChineseCLIP vision attention, MI355X bf16-MFMA pipeline. Round 8:
//  - Bank-conflict fix for BK=32 layouts (qkv_gemm + o_gemm): LDS reads are
//    serviced in 16-lane groups, so the 16B-slot position must vary WITHIN
//    lanes 0..15. 64B rows only contribute a parity bit, and quad was
//    constant per group -> 4-way conflict (R3: 6.6M). Fix: per-row slot
//    swizzle sigma(row)=(row>>1)&3; stage source seg = (lane&3)^((lane>>3)&3),
//    fragment read slot = quad^((n15>>1)&3). Position = (n15&1)*4 ^ slot
//    covers all 8 positions x 2 lanes per 16-lane group -> conflict-free.
//  - Everything else identical to R7 (256x128 BK=32, 2 blk/CU, 16 waves/CU).
// B=32, T=257, D=1024, H=16, HD=64.

#define B_   32
#define T_   257
#define TP   272
#define H_   16
#define HD_  64
#define D_   1024
#define NTOK 8224
#define BH_  512
#define FRAG_PER_BH 17408   // TP*HD elements per (b,h) in frag-major arrays

typedef __bf16 bf16;
typedef __bf16 bf16x4 __attribute__((ext_vector_type(4)));
typedef __bf16 bf16x8 __attribute__((ext_vector_type(8)));
typedef short  s16x4  __attribute__((ext_vector_type(4)));
typedef short  s16x8  __attribute__((ext_vector_type(8)));
typedef float  floatx4 __attribute__((ext_vector_type(4)));

static constexpr size_t SZ_XB   = (size_t)NTOK * D_ * 2;
static constexpr size_t SZ_WQKV = (size_t)3 * D_ * D_ * 2;
static constexpr size_t SZ_W    = (size_t)D_ * D_ * 2;
static constexpr size_t SZ_QK   = (size_t)BH_ * FRAG_PER_BH * 2;

static constexpr size_t OFF_XB   = 0;
static constexpr size_t OFF_WQKV = OFF_XB + SZ_XB;
static constexpr size_t OFF_WO   = OFF_WQKV + SZ_WQKV;
static constexpr size_t OFF_Q    = OFF_WO + SZ_W;
static constexpr size_t OFF_K    = OFF_Q + SZ_QK;
static constexpr size_t OFF_V    = OFF_K + SZ_QK;
static constexpr size_t OFF_CTX  = OFF_V + SZ_QK;

#define GLD16(gp, lp)                                                        \
  __builtin_amdgcn_global_load_lds(                                          \
      (const __attribute__((address_space(1))) void*)(gp),                   \
      (__attribute__((address_space(3))) void*)(lp), 16, 0, 0)

// ---------------- fp32 -> bf16 casts (single launch) ----------------
__global__ void cast_all_kernel(const float* __restrict__ hs,
                                const float* __restrict__ Wq, const float* __restrict__ Wk,
                                const float* __restrict__ Wv, const float* __restrict__ Wo,
                                bf16* __restrict__ xb, bf16* __restrict__ wqkv,
                                bf16* __restrict__ wob) {
  const int y = blockIdx.y;
  const float* s;
  bf16* d;
  int n4;
  if (y == 0) {
    s = hs; d = xb; n4 = NTOK * D_ / 4;
  } else {
    int z = y - 1;
    s = (z == 0) ? Wq : (z == 1) ? Wk : (z == 2) ? Wv : Wo;
    d = (z < 3) ? wqkv + (size_t)z * D_ * D_ : wob;
    n4 = D_ * D_ / 4;
  }
  int i = blockIdx.x * blockDim.x + threadIdx.x;
  int stride = gridDim.x * blockDim.x;
  for (int idx = i; idx < n4; idx += stride) {
    float4 v = reinterpret_cast<const float4*>(s)[idx];
    bf16x4 o;
    o[0] = (bf16)v.x; o[1] = (bf16)v.y; o[2] = (bf16)v.z; o[3] = (bf16)v.w;
    reinterpret_cast<bf16x4*>(d)[idx] = o;
  }
}

// Frag-major layouts (element offsets within one bh's 17408 elems):
// Q/K (A/B-op of 16x16x32): [kt(17)][dc(8)][ki(16)][8]  (t=kt*16+ki, d=dc*8+e)
// V   (A-op of 16x16x16, dt-paired): [kt(17)][p(2)][q2(4)][d16(16)][dp(2)][ki(4)]
//     t = kt*16 + q2*4 + ki, d = p*32 + dp*16 + d16.

// ================= fused QKV GEMM: 256x128 tile, BK=32, 2 blocks/CU ======
// 512 threads = 8 waves (4M x 2N), wave-tile 64x64. K=1024 -> 32 K-tiles.
// LDS (48KB): A [2][256][32] elems at 0, B [2][128][32] at 16384.
// Slot swizzle sigma(row)=(row>>1)&3 (see header). Stage(t+2) issued into
// the buffer this tile just finished reading. vmcnt(3) = t+1 fully landed.

#define KTILE(TT, CC)                                                        \
  do {                                                                       \
    const int ktn_ = ((TT) + 2 < 32) ? (TT) + 2 : 31;                        \
    _Pragma("unroll") for (int mi_ = 0; mi_ < 4; mi_++)                      \
      af[mi_] = *reinterpret_cast<const bf16x8*>(                            \
          smem + (CC) * 8192 + (arow + mi_ * 16) * 32 + qsw);                \
    _Pragma("unroll") for (int nj_ = 0; nj_ < 4; nj_++)                      \
      bfr[nj_] = *reinterpret_cast<const bf16x8*>(                           \
          smem + 16384 + (CC) * 4096 + (brow + nj_ * 16) * 32 + qsw);        \
    asm volatile("s_waitcnt lgkmcnt(0)" ::: "memory");                       \
    __builtin_amdgcn_sched_barrier(0);                                       \
    __builtin_amdgcn_s_barrier();                                            \
    /* buffer CC is dead now -> stage tile TT+2 into it */                   \
    GLD16(aSrc0 + ktn_ * 32, dstA0 + (CC) * 8192);                           \
    GLD16(aSrc1 + ktn_ * 32, dstA1 + (CC) * 8192);                           \
    GLD16(bSrc + ktn_ * 32, dstB + (CC) * 4096);                             \
    __builtin_amdgcn_sched_barrier(0);                                       \
    __builtin_amdgcn_s_setprio(1);                                           \
    _Pragma("unroll") for (int mi_ = 0; mi_ < 4; mi_++)                      \
      _Pragma("unroll") for (int nj_ = 0; nj_ < 4; nj_++)                    \
        acc[mi_][nj_] = __builtin_amdgcn_mfma_f32_16x16x32_bf16(             \
            af[mi_], bfr[nj_], acc[mi_][nj_], 0, 0, 0);                      \
    __builtin_amdgcn_s_setprio(0);                                           \
    asm volatile("s_waitcnt vmcnt(3)" ::: "memory");                         \
    __builtin_amdgcn_s_barrier();                                            \
  } while (0)

__global__ __launch_bounds__(512, 4) void qkv_gemm(
    const bf16* __restrict__ xb, const bf16* __restrict__ wqkv,
    const float* __restrict__ bq, const float* __restrict__ bk,
    const float* __restrict__ bv,
    bf16* __restrict__ Qf, bf16* __restrict__ Kf, bf16* __restrict__ Vf) {
  __shared__ bf16 smem[24576];   // 48KB

  const int linear = blockIdx.x;
  const int mt = linear / 24, nt = linear % 24;
  const int m0 = mt * 256, n0 = nt * 128;
  const int tid = threadIdx.x;
  const int lane = tid & 63, w = tid >> 6;
  const int n15 = lane & 15, quad = lane >> 4;
  const int wr4 = w >> 1, wn = w & 1;

  const int arow = wr4 * 64 + n15;   // A rows this wave reads (base)
  const int brow = wn * 64 + n15;    // B rows this wave reads (base)
  // fragment read slot, swizzled: quad ^ sigma(row); row contributions from
  // multiples of 16 vanish in (row>>1)&3, so sigma = (n15>>1)&3 per lane.
  const int qsw = (quad ^ ((n15 >> 1) & 3)) * 8;

  // staging source pointers (per-thread, fixed; kt advances by +kt*32 elems)
  // lane l stages (row = l>>2, slot = l&3) of its wave's 16-row chunk; the
  // slot holds global segment (l&3) ^ sigma(row) = (l&3) ^ ((l>>3)&3).
  const int srow = lane >> 2;
  const int sseg = ((lane & 3) ^ ((lane >> 3) & 3)) * 8;
  int gmA0 = m0 + (w * 2 + 0) * 16 + srow; if (gmA0 > NTOK - 1) gmA0 = NTOK - 1;
  int gmA1 = m0 + (w * 2 + 1) * 16 + srow; if (gmA1 > NTOK - 1) gmA1 = NTOK - 1;
  const bf16* aSrc0 = xb + (size_t)gmA0 * D_ + sseg;
  const bf16* aSrc1 = xb + (size_t)gmA1 * D_ + sseg;
  const bf16* bSrc  = wqkv + (size_t)(n0 + w * 16 + srow) * D_ + sseg;
  // LDS dests (wave-uniform; HW adds lane*16B)
  bf16* dstA0 = smem + (w * 2 + 0) * 512;
  bf16* dstA1 = smem + (w * 2 + 1) * 512;
  bf16* dstB  = smem + 16384 + w * 512;

  floatx4 acc[4][4] = {};
  bf16x8 af[4], bfr[4];

  // prologue: tile0 -> buf0, tile1 -> buf1; vmcnt(3) = tile0 landed.
  GLD16(aSrc0, dstA0); GLD16(aSrc1, dstA1); GLD16(bSrc, dstB);
  GLD16(aSrc0 + 32, dstA0 + 8192); GLD16(aSrc1 + 32, dstA1 + 8192);
  GLD16(bSrc + 32, dstB + 4096);
  asm volatile("s_waitcnt vmcnt(3)" ::: "memory");
  __builtin_amdgcn_s_barrier();

  for (int t = 0; t < 32; t += 2) {
    KTILE(t, 0);
    KTILE(t + 1, 1);
  }

  // drain tail junk stages before reusing LDS.
  asm volatile("s_waitcnt vmcnt(0)" ::: "memory");
  __builtin_amdgcn_s_barrier();

  // ---- epilogue: two 128-row half-passes, frag-major stores ----
  const int z = nt >> 3;                 // 0=Q 1=K 2=V
  bf16* zdst = (z == 0) ? Qf : (z == 1) ? Kf : Vf;
  const float scale = (z == 0) ? 0.125f : 1.0f;
  const float* bias = (z == 0) ? bq : (z == 1) ? bk : bv;
  const int znb = (nt & 7) * 128;        // col base within the 1024-wide slab

  for (int h = 0; h < 2; h++) {
    // waves with (wr4>>1)==h own rows [h*128, h*128+128)
    if ((wr4 >> 1) == h) {
      float bvv[4];
#pragma unroll
      for (int nj = 0; nj < 4; nj++)
        bvv[nj] = bias[znb + wn * 64 + nj * 16 + n15];
#pragma unroll
      for (int mi = 0; mi < 4; mi++)
#pragma unroll
        for (int nj = 0; nj < 4; nj++) {
          int colL = wn * 64 + nj * 16 + n15;
#pragma unroll
          for (int r = 0; r < 4; r++) {
            int rowL = (wr4 & 1) * 64 + mi * 16 + quad * 4 + r;
            smem[rowL * 136 + colL] = (bf16)((acc[mi][nj][r] + bvv[nj]) * scale);
          }
        }
    }
    __syncthreads();

    const int mh0 = m0 + h * 128;
    int nU = 0, nA = 0, tgA0 = 0, tA = 0, tEndA = 0, tEndB = 0, bA = 0;
    int span = NTOK - mh0;
    if (span > 0) {
      if (span > 128) span = 128;
      bA = mh0 / T_;
      tA = mh0 - bA * T_;
      tEndA = (tA + span < T_) ? tA + span : T_;
      tgA0 = tA >> 4;
      nA = ((tEndA - 1) >> 4) - tgA0 + 1;
      nU = nA;
      if (tA + span > T_ && bA + 1 < B_) {
        tEndB = tA + span - T_;
        nU += ((tEndB - 1) >> 4) + 1;
      }
    }

    for (int u = w; u < nU * 2; u += 8) {
      int g = u >> 1, hh = u & 1;
      int bb, tg, tlo, thi;
      if (g < nA) {
        bb = bA; tg = tgA0 + g;
        tlo = (tA > tg * 16) ? tA : tg * 16;
        int te = tg * 16 + 16; thi = (te < tEndA) ? te : tEndA;
      } else {
        bb = bA + 1; tg = g - nA; tlo = tg * 16;
        int te = tg * 16 + 16; thi = (te < tEndB) ? te : tEndB;
      }
      const int hgl = (nt & 7) * 2 + hh;   // head within slab
      bf16* gb = zdst + (size_t)(bb * H_ + hgl) * FRAG_PER_BH + tg * 1024;
      const int hc = hh * 64;
      if (z != 2) {
        int ki = lane & 15, dc = lane >> 4;
        int tt = tg * 16 + ki;
        if (tt >= tlo && tt < thi) {
          int rowL = bb * T_ + tt - mh0;
          bf16x8 v0 = *reinterpret_cast<const bf16x8*>(smem + rowL * 136 + hc + dc * 8);
          bf16x8 v1 = *reinterpret_cast<const bf16x8*>(smem + rowL * 136 + hc + 32 + dc * 8);
          *reinterpret_cast<bf16x8*>(gb + dc * 128 + ki * 8) = v0;
          *reinterpret_cast<bf16x8*>(gb + 512 + dc * 128 + ki * 8) = v1;
        }
      } else {
        int q2 = (lane >> 4) & 3, d16 = lane & 15;
        int tb = tg * 16 + q2 * 4;
        bool full = (tb >= tlo) && (tb + 3 < thi);
#pragma unroll
        for (int p = 0; p < 2; p++) {
          bf16x8 vv;
#pragma unroll
          for (int dp = 0; dp < 2; dp++)
#pragma unroll
            for (int ki = 0; ki < 4; ki++) {
              int tt = tb + ki;
              int rr = (bb * T_ + tt - mh0) & 127;   // safe for masked elems
              vv[dp * 4 + ki] = smem[rr * 136 + hc + p * 32 + dp * 16 + d16];
            }
          bf16* cp = gb + (p * 4 + q2) * 128 + d16 * 8;
          if (full) {
            *reinterpret_cast<bf16x8*>(cp) = vv;
          } else {
#pragma unroll
            for (int dp = 0; dp < 2; dp++)
#pragma unroll
              for (int ki = 0; ki < 4; ki++) {
                int tt = tb + ki;
                if (tt >= tlo && tt < thi) cp[dp * 4 + ki] = vv[dp * 4 + ki];
              }
          }
        }
      }
    }
    __syncthreads();
  }
}

// ---------------- fused attention (LDS-staged K/V) ----------------
// grid = 512 (one block per bh), 4 waves; wave w handles q-tiles w, w+4, ...
__global__ __launch_bounds__(256) void attn_kernel(
    const bf16* __restrict__ Qf, const bf16* __restrict__ Kf,
    const bf16* __restrict__ Vf, bf16* __restrict__ ctx) {
  __shared__ bf16 smem[34816];   // K (17408) then V (17408)

  const int bh = blockIdx.x;
  const int tid = threadIdx.x;
  const int lane = tid & 63, w = tid >> 6;
  const int n15 = lane & 15, quad = lane >> 4;
  const int b = bh >> 4, h = bh & 15;

  const bf16* Qb = Qf + (size_t)bh * FRAG_PER_BH;
  const bf16* Kb = Kf + (size_t)bh * FRAG_PER_BH;
  const bf16* Vb = Vf + (size_t)bh * FRAG_PER_BH;

  // stage K and V: 68 chunks of 1KB, 17 per wave
#pragma unroll
  for (int j = 0; j < 17; j++) {
    int c = w * 17 + j;
    const bf16* src = (c < 34) ? (Kb + c * 512) : (Vb + (c - 34) * 512);
    GLD16(src + lane * 8, smem + c * 512);
  }
  __syncthreads();
  const bf16* Ksh = smem;
  const bf16* Vsh = smem + 17408;

  const int fo = quad * 128 + n15 * 8;

  for (int qt = w; qt < 17; qt += 4) {
    bf16x8 qb0 = *reinterpret_cast<const bf16x8*>(Qb + qt * 1024 + fo);
    bf16x8 qb1 = *reinterpret_cast<const bf16x8*>(Qb + qt * 1024 + 512 + fo);

    floatx4 s[17];
#pragma unroll
    for (int kt = 0; kt < 17; kt++) {
      bf16x8 ka0 = *reinterpret_cast<const bf16x8*>(Ksh + kt * 1024 + fo);
      bf16x8 ka1 = *reinterpret_cast<const bf16x8*>(Ksh + kt * 1024 + 512 + fo);
      floatx4 c = {};
      c = __builtin_amdgcn_mfma_f32_16x16x32_bf16(ka0, qb0, c, 0, 0, 0);
      c = __builtin_amdgcn_mfma_f32_16x16x32_bf16(ka1, qb1, c, 0, 0, 0);
      s[kt] = c;
    }
    // keys 257..271 invalid: tile 16 holds keys 256+quad*4+r; only 256 valid
    s[16][1] = -1e30f; s[16][2] = -1e30f; s[16][3] = -1e30f;
    if (quad != 0) s[16][0] = -1e30f;

    float m0 = -1e30f;
#pragma unroll
    for (int kt = 0; kt < 17; kt++)
#pragma unroll
      for (int r = 0; r < 4; r++) m0 = fmaxf(m0, s[kt][r]);
    m0 = fmaxf(m0, __shfl_xor(m0, 16));
    m0 = fmaxf(m0, __shfl_xor(m0, 32));

    float sum = 0.f;
    s16x4 pb[17];
#pragma unroll
    for (int kt = 0; kt < 17; kt++) {
      bf16x4 ph;
#pragma unroll
      for (int r = 0; r < 4; r++) {
        float p = __expf(s[kt][r] - m0);
        sum += p;
        ph[r] = (bf16)p;
      }
      pb[kt] = __builtin_bit_cast(s16x4, ph);
    }
    sum += __shfl_xor(sum, 16);
    sum += __shfl_xor(sum, 32);

    floatx4 o[4] = {};
#pragma unroll
    for (int kt = 0; kt < 17; kt++) {
#pragma unroll
      for (int p = 0; p < 2; p++) {
        bf16x8 vv = *reinterpret_cast<const bf16x8*>(
            Vsh + ((kt * 2 + p) * 4 + quad) * 128 + n15 * 8);
        s16x8 v16 = __builtin_bit_cast(s16x8, vv);
        s16x4 vlo = __builtin_shufflevector(v16, v16, 0, 1, 2, 3);
        s16x4 vhi = __builtin_shufflevector(v16, v16, 4, 5, 6, 7);
        o[p * 2]     = __builtin_amdgcn_mfma_f32_16x16x16bf16_1k(vlo, pb[kt], o[p * 2], 0, 0, 0);
        o[p * 2 + 1] = __builtin_amdgcn_mfma_f32_16x16x16bf16_1k(vhi, pb[kt], o[p * 2 + 1], 0, 0, 0);
      }
    }

    int q = qt * 16 + n15;
    if (q < T_) {
      float inv = 1.0f / sum;
      size_t ob = ((size_t)(b * T_ + q)) * D_ + h * 64 + quad * 4;
#pragma unroll
      for (int dt = 0; dt < 4; dt++) {
        bf16x4 ov;
#pragma unroll
        for (int r = 0; r < 4; r++) ov[r] = (bf16)(o[dt][r] * inv);
        *reinterpret_cast<bf16x4*>(ctx + ob + dt * 16) = ov;
      }
    }
  }
}

// ---------------- output projection GEMM (fp32 out) ----------------
__global__ __launch_bounds__(256) void o_gemm(
    const bf16* __restrict__ ctx, const bf16* __restrict__ wo,
    const float* __restrict__ bo, float* __restrict__ out) {
  __shared__ bf16 Ash[128 * 32];
  __shared__ bf16 Bsh[128 * 32];

  const int linear = blockIdx.x;
  const int nbase = (linear & 7) * 128;
  const int mbase = (linear >> 3) * 128;
  const int tid = threadIdx.x;
  const int lane = tid & 63;
  const int w = tid >> 6;
  const int wr = w >> 1, wc = w & 1;
  const int n15 = lane & 15, quad = lane >> 4;

  // slot-swizzled staging/read (same sigma(row)=(row>>1)&3 as qkv_gemm)
  const int lrow = lane >> 2;
  const int lseg = ((lane & 3) ^ ((lane >> 3) & 3)) * 8;
  const int qsw = (quad ^ ((n15 >> 1) & 3)) * 8;

  floatx4 acc[4][4] = {};

  for (int k0 = 0; k0 < D_; k0 += 32) {
#pragma unroll
    for (int c = 0; c < 2; c++) {
      int r0 = w * 32 + c * 16;
      int row = r0 + lrow;
      int gm = mbase + row; if (gm > NTOK - 1) gm = NTOK - 1;
      GLD16(ctx + (size_t)gm * D_ + k0 + lseg, Ash + r0 * 32);
      GLD16(wo + (size_t)(nbase + row) * D_ + k0 + lseg, Bsh + r0 * 32);
    }
    __syncthreads();
    bf16x8 af[4], bfr[4];
#pragma unroll
    for (int i = 0; i < 4; i++) {
      af[i]  = *reinterpret_cast<const bf16x8*>(Ash + (wr * 64 + i * 16 + n15) * 32 + qsw);
      bfr[i] = *reinterpret_cast<const bf16x8*>(Bsh + (wc * 64 + i * 16 + n15) * 32 + qsw);
    }
#pragma unroll
    for (int i = 0; i < 4; i++)
#pragma unroll
      for (int j = 0; j < 4; j++)
        acc[i][j] = __builtin_amdgcn_mfma_f32_16x16x32_bf16(af[i], bfr[j], acc[i][j], 0, 0, 0);
    __syncthreads();
  }

#pragma unroll
  for (int i = 0; i < 4; i++) {
    int rowb = mbase + wr * 64 + i * 16 + quad * 4;
#pragma unroll
    for (int j = 0; j < 4; j++) {
      int col = nbase + wc * 64 + j * 16 + n15;
      float bval = bo[col];
#pragma unroll
      for (int r = 0; r < 4; r++) {
        int m = rowb + r;
        if (m < NTOK) out[(size_t)m * D_ + col] = acc[i][j][r] + bval;
      }
    }
  }
}

extern "C" void kernel_launch(void* const* d_in, const int* in_sizes, int n_in,
                              void* d_out, int out_size, void* d_ws, size_t ws_size,
                              hipStream_t stream) {
  const float* hs = (const float*)d_in[0];
  const float* Wq = (const float*)d_in[1];
  const float* bq = (const float*)d_in[2];
  const float* Wk = (const float*)d_in[3];
  const float* bk = (const float*)d_in[4];
  const float* Wv = (const float*)d_in[5];
  const float* bv = (const float*)d_in[6];
  const float* Wo = (const float*)d_in[7];
  const float* bo = (const float*)d_in[8];

  char* ws = (char*)d_ws;
  bf16* xb   = (bf16*)(ws + OFF_XB);
  bf16* wqkv = (bf16*)(ws + OFF_WQKV);
  bf16* wob  = (bf16*)(ws + OFF_WO);
  bf16* Qfw  = (bf16*)(ws + OFF_Q);
  bf16* Kfw  = (bf16*)(ws + OFF_K);
  bf16* Vfw  = (bf16*)(ws + OFF_V);
  bf16* ctx  = (bf16*)(ws + OFF_CTX);

  cast_all_kernel<<<dim3(512, 5), 256, 0, stream>>>(hs, Wq, Wk, Wv, Wo,
                                                    xb, wqkv, wob);

  qkv_gemm<<<792, 512, 0, stream>>>(xb, wqkv, bq, bk, bv, Qfw, Kfw, Vfw);
  attn_kernel<<<BH_, 256, 0, stream>>>(Qfw, Kfw, Vfw, ctx);
  o_gemm<<<520, 256, 0, stream>>>(ctx, wob, bo, (float*)d_out);
}